// Round 7
// baseline (3386.123 us; speedup 1.0000x reference)
//
#include <hip/hip_runtime.h>
#include <cstdint>
#include <cstddef>

// ============================================================================
// EFLSTM: concat(x_text,x_audio,x_vision) -> LSTM(H=1024, T=256, B=256) -> MLP
//
// Round 7 = Round 6 (4x1 wave split) + THE FIX: a __syncthreads() between the
// global_load_lds staging and the ds_read consumption. R6 removed it and read
// uninitialized LDS (async LDS writes are vmcnt-tracked; the compiler does NOT
// auto-insert a vmcnt wait before dependent ds_reads) -> NaN entered c at
// step 0 and mlp1's fmaxf(NaN,0)=0 masked it into an all-zero output.
//
// Structure (unchanged from R6 otherwise):
//  - wave w owns mtile g*4+w x all 4 gate quadrants; wave-private A regions.
//  - elementwise fully in-register; gates-LDS buffer deleted; c in C-frag slots.
//  - h' packed via 2 shfl_xor -> one 8B agent store per 4 lanes.
//  - per step: S1 (post-stage drain) + S4 (pre-flag drain) + flag poll.
//  - No cache-wide fences anywhere (R5's 4.5x win).
// LDS: 4 x 32 KB wave-private A regions = 131072 B. 1 block/CU.
// ============================================================================

typedef __attribute__((ext_vector_type(8))) short short8;   // 8 x bf16
typedef __attribute__((ext_vector_type(4))) float f32x4;

#define MFMA_BF16(A,B,C) __builtin_amdgcn_mfma_f32_16x16x32_bf16((A),(B),(C),0,0,0)

// ---- workspace layout (bytes) ----
#define OFF_FLAGS 0u            // 256 * 4
#define OFF_HBUF0 4096u         // 256*1024*2 = 524288   (A-frag-linear bf16)
#define OFF_CBUF  528384u       // 256*1024*4 = 1048576  (fp32 cell, C-frag slots)
#define ZERO_SPAN 1576960u      // flags + hbuf0 + cbuf zeroed every launch
#define OFF_HBUF1 1576960u      // 524288
#define OFF_HFIN  2101248u      // 256*1024*4 = 1048576  (fp32 h_last)
#define OFF_HID   3149824u      // 256*512*4  = 524288   (fp32 mlp hidden)
#define OFF_BIAS  3674112u      // 4096*4
#define OFF_WHH   3690496u      // 64 slices * 64*1024 * 2 = 8388608
#define OFF_WIH   12079104u     // 256*13*64*8*2 = 3407872
#define OFF_XB    15486976u     // 4096*13*64*8*2 = 54525952
#define OFF_XG    70012928u     // 32*256*16*64*8 = 67108864 (bf16 C-frags)
#define WS_NEED   137121792ull

static __device__ __forceinline__ uint16_t f2bf(float f) {
  uint32_t u = __builtin_bit_cast(uint32_t, f);
  uint32_t r = u + 0x7FFFu + ((u >> 16) & 1u);   // round-nearest-even
  return (uint16_t)(r >> 16);
}
static __device__ __forceinline__ float bf2f_lo(uint32_t u) {
  return __builtin_bit_cast(float, u << 16);
}
static __device__ __forceinline__ float bf2f_hi(uint32_t u) {
  return __builtin_bit_cast(float, u & 0xFFFF0000u);
}
static __device__ __forceinline__ float sigm(float x) {
  return 1.0f / (1.0f + __expf(-x));
}
static __device__ __forceinline__ float tanh_f(float x) {
  float e = __expf(2.0f * x);
  return 1.0f - 2.0f / (e + 1.0f);
}
// async global->LDS, 16B/lane, aux=0x11 (SC0|SC1): IF-coherent read,
// bypasses the non-coherent per-XCD L2.
static __device__ __forceinline__ void gld_lds16_coh(const void* gsrc, void* ldst) {
  __builtin_amdgcn_global_load_lds(
      (const __attribute__((address_space(1))) uint32_t*)gsrc,
      (__attribute__((address_space(3))) uint32_t*)ldst, 16, 0, 0x11);
}

// ---------------------------------------------------------------------------
// pack x (3 tensors, fp32 [B,T,D_i]) -> xb bf16 A-frag-linear:
//   [mtile 4096][ks 13][lane 64][8], m = t*256+b, k padded to 416 with zeros
// ---------------------------------------------------------------------------
__global__ __launch_bounds__(256) void pack_xb_kernel(
    const float* __restrict__ xt, const float* __restrict__ xa,
    const float* __restrict__ xv, uint16_t* __restrict__ xb)
{
  int id = blockIdx.x * 256 + threadIdx.x;          // < 4096*13*64 = 3407872
  int lane = id & 63;
  int rem  = id >> 6;
  int ks = rem % 13;
  int mt = rem / 13;
  int m = mt * 16 + (lane & 15);
  int t = m >> 8;
  int b = m & 255;
  int k0 = ks * 32 + (lane >> 4) * 8;
  size_t base = (size_t)b * 256 + t;
  uint16_t vals[8];
#pragma unroll
  for (int e = 0; e < 8; ++e) {
    int k = k0 + e;
    float v;
    if (k < 300)      v = xt[base * 300 + k];
    else if (k < 374) v = xa[base * 74  + (k - 300)];
    else if (k < 409) v = xv[base * 35  + (k - 374)];
    else              v = 0.0f;
    vals[e] = f2bf(v);
  }
  uint32_t* d32 = (uint32_t*)(xb + (size_t)id * 8);
#pragma unroll
  for (int i = 0; i < 4; ++i)
    d32[i] = (uint32_t)vals[2*i] | ((uint32_t)vals[2*i+1] << 16);
}

// ---------------------------------------------------------------------------
// pack W_hh fp32 [4096,1024] -> bf16 B-frag-linear per scan block s:
//   [s 64][q 4][ks 32][lane 64][8], row = q*1024 + 16*s + (lane&15)
// ---------------------------------------------------------------------------
__global__ __launch_bounds__(256) void pack_whh_kernel(
    const float* __restrict__ whh, uint16_t* __restrict__ wp)
{
  int id = blockIdx.x * 256 + threadIdx.x;          // < 64*4*32*64 = 524288
  int lane = id & 63;
  int ks = (id >> 6) & 31;
  int q  = (id >> 11) & 3;
  int s  = id >> 13;
  int row = q * 1024 + s * 16 + (lane & 15);
  int k0 = ks * 32 + (lane >> 4) * 8;
  const float* src = whh + (size_t)row * 1024 + k0;
  uint16_t vals[8];
#pragma unroll
  for (int e = 0; e < 8; ++e) vals[e] = f2bf(src[e]);
  uint32_t* d32 = (uint32_t*)(wp + (size_t)id * 8);
#pragma unroll
  for (int i = 0; i < 4; ++i)
    d32[i] = (uint32_t)vals[2*i] | ((uint32_t)vals[2*i+1] << 16);
}

// ---------------------------------------------------------------------------
// pack W_ih fp32 [4096,409] -> bf16 B-frag-linear [nt 256][ks 13][lane][8]
// ---------------------------------------------------------------------------
__global__ __launch_bounds__(256) void pack_wih_kernel(
    const float* __restrict__ wih, uint16_t* __restrict__ wp)
{
  int id = blockIdx.x * 256 + threadIdx.x;          // < 256*13*64 = 212992
  int lane = id & 63;
  int rem = id >> 6;
  int ks = rem % 13;
  int nt = rem / 13;
  int n = nt * 16 + (lane & 15);
  int k0 = ks * 32 + (lane >> 4) * 8;
  uint16_t vals[8];
#pragma unroll
  for (int e = 0; e < 8; ++e) {
    int k = k0 + e;
    vals[e] = (k < 409) ? f2bf(wih[(size_t)n * 409 + k]) : (uint16_t)0;
  }
  uint32_t* d32 = (uint32_t*)(wp + (size_t)id * 8);
#pragma unroll
  for (int i = 0; i < 4; ++i)
    d32[i] = (uint32_t)vals[2*i] | ((uint32_t)vals[2*i+1] << 16);
}

__global__ __launch_bounds__(256) void pack_bias_kernel(
    const float* __restrict__ b_ih, const float* __restrict__ b_hh,
    float* __restrict__ bias)
{
  int id = blockIdx.x * 256 + threadIdx.x;          // < 4096
  bias[id] = b_ih[id] + b_hh[id];
}

// ---------------------------------------------------------------------------
// xg GEMM for one 32-step chunk: M=8192 (m=t*256+b), N=4096, K=416 (13 ksteps)
// grid (64, 32), 4 waves, wave tile 64x64. C written C-frag-linear bf16:
//   [t 32][nt 256][bt 16][lane 64][bf16x4]
// ---------------------------------------------------------------------------
__global__ __launch_bounds__(256) void xg_gemm_kernel(
    const short8* __restrict__ xb, const short8* __restrict__ wih,
    const float* __restrict__ bias, uint2* __restrict__ xg, int chunk)
{
  int tid = threadIdx.x;
  int lane = tid & 63;
  int w = tid >> 6;
  int wm = w & 1, wn = w >> 1;
  int bm = blockIdx.x, bn = blockIdx.y;
  int mtb = bm * 8 + wm * 4;          // local mtile base, 0..511
  int ntb = bn * 8 + wn * 4;          // ntile base, 0..255
  int col = lane & 15;

  f32x4 acc[4][4];
#pragma unroll
  for (int b = 0; b < 4; ++b) {
    float bv = bias[(ntb + b) * 16 + col];
    f32x4 v = {bv, bv, bv, bv};
#pragma unroll
    for (int a = 0; a < 4; ++a) acc[a][b] = v;
  }
  size_t mt_glob = (size_t)chunk * 512 + mtb;
  for (int ks = 0; ks < 13; ++ks) {
    short8 Af[4], Bf[4];
#pragma unroll
    for (int a = 0; a < 4; ++a)
      Af[a] = xb[((mt_glob + a) * 13 + ks) * 64 + lane];
#pragma unroll
    for (int b = 0; b < 4; ++b)
      Bf[b] = wih[(((size_t)(ntb + b)) * 13 + ks) * 64 + lane];
#pragma unroll
    for (int a = 0; a < 4; ++a)
#pragma unroll
      for (int b = 0; b < 4; ++b)
        acc[a][b] = MFMA_BF16(Af[a], Bf[b], acc[a][b]);
  }
#pragma unroll
  for (int a = 0; a < 4; ++a) {
    int mt = mtb + a;
    int t_loc = mt >> 4;
    int bt = mt & 15;
#pragma unroll
    for (int b = 0; b < 4; ++b) {
      size_t idx = (((size_t)t_loc * 256 + (ntb + b)) * 16 + bt) * 64 + lane;
      f32x4 v = acc[a][b];
      uint2 o;
      o.x = (uint32_t)f2bf(v[0]) | ((uint32_t)f2bf(v[1]) << 16);
      o.y = (uint32_t)f2bf(v[2]) | ((uint32_t)f2bf(v[3]) << 16);
      xg[idx] = o;
    }
  }
}

// ---------------------------------------------------------------------------
// Persistent scan, 4x1 wave split: 256 blocks x 256 threads, 1 block/CU.
// group g = bid>>6 owns batch rows [64g,64g+64); slice s = bid&63 owns hidden
// units [16s,16s+16). Wave w handles mtile g*4+w (16 batch rows) x all 4 gate
// quadrants. Per step:
//   issue 32 gld_lds (own 32 KB A slab) -> S1 (vmcnt drain; REQUIRED — the
//   compiler does not order ds_read after async LDS writes)
//   -> ds_read+4xMFMA x32 (W from L2) -> in-register LSTM elementwise
//   -> shfl-packed 8B h' agent stores -> S4 (drain) -> flag release
//   -> xg prefetch -> all-lane poll
// ---------------------------------------------------------------------------
__global__ __launch_bounds__(256, 1) void scan_kernel(
    const uint16_t* __restrict__ whh_p, const uint2* __restrict__ xg,
    uint16_t* __restrict__ hbuf0, uint16_t* __restrict__ hbuf1,
    float* __restrict__ c_buf, float* __restrict__ h_final,
    uint32_t* flags, int chunk)
{
  extern __shared__ char smem[];   // 4 x 32768 B wave-private A regions

  const int tid = threadIdx.x;
  const int bid = blockIdx.x;
  const int g = bid >> 6, s = bid & 63;
  const int lane = tid & 63, w = tid >> 6;

  // W slice base: frag for quadrant q, kstep ks at [(q*32+ks)*64 + lane]
  const short8* wsrc = (const short8*)(whh_p + (size_t)s * 65536);

  // c-state in C-frag-linear slots: [bid][wave][lane][4] fp32
  f32x4* cslot = (f32x4*)c_buf + ((size_t)bid * 4 + w) * 64 + lane;
  f32x4 c4 = *cslot;

  const int r0 = (lane >> 4) * 4;        // C-frag row base (0,4,8,12)
  const int cc = lane & 15;              // C-frag col = unit within slice

  // h'-store geometry: k = 16*s + cc
  const int kk = 16 * s + cc;
  const int ksh = kk >> 5;
  const int quad = (kk >> 3) & 3;
  const int ee = kk & 7;                 // 0 or 4 on storing lanes (cc%4==0)
  const size_t hslab = ((size_t)(g * 4 + w) * 32 + ksh) * 64;  // halfword*8 units

  const short8* Afrag = (const short8*)(smem + w * 32768);
  const int myflag = g * 64 + lane;

  // xg prefetch for step 0: acc[q] seed (bias folded in at gemm time)
  uint2 xp[4];
#pragma unroll
  for (int q = 0; q < 4; ++q)
    xp[q] = xg[(((size_t)0 * 256 + (q * 64 + s)) * 16 + (g * 4 + w)) * 64 + lane];

  for (int l = 0; l < 32; ++l) {
    const int ts = chunk * 32 + l;
    const uint16_t* hin = (ts & 1) ? hbuf1 : hbuf0;
    uint16_t* hout = (ts & 1) ? hbuf0 : hbuf1;

    // ---- stage own A slab (mtile g*4+w, 32 ks x 1 KB) into wave region ----
    {
      const uint16_t* gbase = hin + ((size_t)(g * 4 + w) * 32 * 64 + lane) * 8;
      char* lbase = smem + w * 32768;
#pragma unroll
      for (int p = 0; p < 32; ++p)
        gld_lds16_coh(gbase + (size_t)p * 512, lbase + p * 1024);
    }

    // acc init from prefetched xg
    f32x4 acc[4];
#pragma unroll
    for (int q = 0; q < 4; ++q) {
      uint2 p = xp[q];
      f32x4 v = {bf2f_lo(p.x), bf2f_hi(p.x), bf2f_lo(p.y), bf2f_hi(p.y)};
      acc[q] = v;
    }

    __syncthreads();   // S1: vmcnt(0) drain — async LDS writes are NOT
                       // auto-ordered before ds_read (R6's NaN bug)

    // ---- K loop: A from own LDS region, W from L2 (4 waves lockstep->L1) --
#pragma unroll
    for (int ks = 0; ks < 32; ++ks) {
      short8 A = Afrag[ks * 64 + lane];
      acc[0] = MFMA_BF16(A, wsrc[(ks) * 64 + lane], acc[0]);
      acc[1] = MFMA_BF16(A, wsrc[(32 + ks) * 64 + lane], acc[1]);
      acc[2] = MFMA_BF16(A, wsrc[(64 + ks) * 64 + lane], acc[2]);
      acc[3] = MFMA_BF16(A, wsrc[(96 + ks) * 64 + lane], acc[3]);
    }

    // ---- in-register LSTM elementwise (i,f,g,o = acc[0..3], same lane/reg) -
    float hv[4];
#pragma unroll
    for (int rg = 0; rg < 4; ++rg) {
      float cn = sigm(acc[1][rg]) * c4[rg] + sigm(acc[0][rg]) * tanh_f(acc[2][rg]);
      c4[rg] = cn;
      hv[rg] = sigm(acc[3][rg]) * tanh_f(cn);
    }

    // ---- h' -> A-frag-linear: shfl-pack 4 units -> one 8B store per 4 lanes
#pragma unroll
    for (int rg = 0; rg < 4; ++rg) {
      uint32_t v = (uint32_t)f2bf(hv[rg]);
      uint32_t w0 = v | ((uint32_t)__shfl_xor((int)v, 1, 64) << 16);
      uint32_t w1 = (uint32_t)__shfl_xor((int)w0, 2, 64);
      if ((lane & 3) == 0) {
        unsigned long long v64 =
            (unsigned long long)w0 | ((unsigned long long)w1 << 32);
        size_t slot = (hslab + (size_t)(quad * 16 + r0 + rg)) * 8 + ee;
        __hip_atomic_store((unsigned long long*)(hout + slot), v64,
                           __ATOMIC_RELAXED, __HIP_MEMORY_SCOPE_AGENT);
      }
    }
    if (chunk == 7 && l == 31) {
#pragma unroll
      for (int rg = 0; rg < 4; ++rg)
        h_final[(size_t)(g * 64 + w * 16 + r0 + rg) * 1024 + 16 * s + cc] = hv[rg];
    }
    if (l != 31) {
      // ---- group-local barrier (64 blocks of group g), fence-free ----
      __syncthreads();   // S4: drains every wave's h' stores (vmcnt0 pre-barrier)
      if (tid == 0) {
        __hip_atomic_store(&flags[bid], (uint32_t)(ts + 1),
                           __ATOMIC_RELAXED, __HIP_MEMORY_SCOPE_AGENT);
      }
      // prefetch next step's xg while waiting (xg constant during scan)
      {
        int ln = l + 1;
#pragma unroll
        for (int q = 0; q < 4; ++q)
          xp[q] = xg[(((size_t)ln * 256 + (q * 64 + s)) * 16 + (g * 4 + w)) * 64 + lane];
      }
      // each lane polls one peer flag; a wave exits only when all 64 peers
      // have released -> safe to re-stage (LDS regions are wave-private)
      while (__hip_atomic_load(&flags[myflag], __ATOMIC_RELAXED,
                               __HIP_MEMORY_SCOPE_AGENT) < (uint32_t)(ts + 1)) {
        __builtin_amdgcn_s_sleep(1);
      }
    }
  }
  *cslot = c4;
}

// ---------------------------------------------------------------------------
// MLP layer 1: hidden = relu(h_last @ W1^T + b1), fp32 VALU.
// ---------------------------------------------------------------------------
__global__ __launch_bounds__(256) void mlp1_kernel(
    const float* __restrict__ h_final, const float* __restrict__ W1,
    const float* __restrict__ b1, float* __restrict__ hidden)
{
  __shared__ float hl[8 * 1024];       // 32 KB
  __shared__ float part[4 * 64 * 8];   // 8 KB
  int tid = threadIdx.x;
  int rb = blockIdx.x;                 // 0..31
  int cb = blockIdx.y;                 // 0..7
  const f32x4* hsrc = (const f32x4*)(h_final + (size_t)rb * 8 * 1024);
  for (int i = tid; i < 2048; i += 256) ((f32x4*)hl)[i] = hsrc[i];
  __syncthreads();
  int cell_l = tid & 63;
  int kq = tid >> 6;                   // k quarter
  int cell = cb * 64 + cell_l;
  float accv[8] = {0,0,0,0,0,0,0,0};
  const f32x4* wrow = (const f32x4*)(W1 + (size_t)cell * 1024) + kq * 64;
  const f32x4* hl4 = (const f32x4*)hl;
  for (int k4 = 0; k4 < 64; ++k4) {
    f32x4 wv = wrow[k4];
    int kidx = kq * 64 + k4;
#pragma unroll
    for (int r = 0; r < 8; ++r) {
      f32x4 hv = hl4[r * 256 + kidx];
      accv[r] += wv[0] * hv[0] + wv[1] * hv[1] + wv[2] * hv[2] + wv[3] * hv[3];
    }
  }
#pragma unroll
  for (int r = 0; r < 8; ++r) part[(kq * 64 + cell_l) * 8 + r] = accv[r];
  __syncthreads();
#pragma unroll
  for (int rr = 0; rr < 2; ++rr) {
    int r = kq * 2 + rr;
    float sum = b1[cell];
    for (int q = 0; q < 4; ++q) sum += part[(q * 64 + cell_l) * 8 + r];
    hidden[(size_t)(rb * 8 + r) * 512 + cell] = fmaxf(sum, 0.0f);
  }
}

// MLP layer 2: out[b] = hidden[b] . W2 + b2
__global__ __launch_bounds__(256) void mlp2_kernel(
    const float* __restrict__ hidden, const float* __restrict__ W2,
    const float* __restrict__ b2, float* __restrict__ out)
{
  __shared__ float w2l[512];
  int tid = threadIdx.x;
  for (int i = tid; i < 512; i += 256) w2l[i] = W2[i];
  __syncthreads();
  const f32x4* hrow = (const f32x4*)(hidden + (size_t)tid * 512);
  const f32x4* w4 = (const f32x4*)w2l;
  float acc = b2[0];
  for (int k = 0; k < 128; ++k) {
    f32x4 a = hrow[k], b = w4[k];
    acc += a[0] * b[0] + a[1] * b[1] + a[2] * b[2] + a[3] * b[3];
  }
  out[tid] = acc;
}

// ---------------------------------------------------------------------------
extern "C" void kernel_launch(void* const* d_in, const int* in_sizes, int n_in,
                              void* d_out, int out_size, void* d_ws, size_t ws_size,
                              hipStream_t stream)
{
  (void)in_sizes; (void)n_in; (void)out_size;
  if (ws_size < WS_NEED) return;   // workspace too small -> loud bench failure

  const float* xt   = (const float*)d_in[0];
  const float* xa   = (const float*)d_in[1];
  const float* xv   = (const float*)d_in[2];
  const float* W_ih = (const float*)d_in[3];
  const float* W_hh = (const float*)d_in[4];
  const float* b_ih = (const float*)d_in[5];
  const float* b_hh = (const float*)d_in[6];
  const float* W1   = (const float*)d_in[7];
  const float* b1   = (const float*)d_in[8];
  const float* W2   = (const float*)d_in[9];
  const float* b2   = (const float*)d_in[10];
  float* out = (float*)d_out;
  char* ws = (char*)d_ws;

  uint32_t* flags   = (uint32_t*)(ws + OFF_FLAGS);
  uint16_t* hb0     = (uint16_t*)(ws + OFF_HBUF0);
  uint16_t* hb1     = (uint16_t*)(ws + OFF_HBUF1);
  float*    c_buf   = (float*)(ws + OFF_CBUF);
  float*    h_final = (float*)(ws + OFF_HFIN);
  float*    hidden  = (float*)(ws + OFF_HID);
  float*    bias    = (float*)(ws + OFF_BIAS);
  uint16_t* whh_p   = (uint16_t*)(ws + OFF_WHH);
  uint16_t* wih_p   = (uint16_t*)(ws + OFF_WIH);
  uint16_t* xb      = (uint16_t*)(ws + OFF_XB);
  uint2*    xg      = (uint2*)(ws + OFF_XG);

  // allow >64KB dynamic LDS for the scan kernel (idempotent, capture-safe)
  hipFuncSetAttribute((const void*)scan_kernel,
                      hipFuncAttributeMaxDynamicSharedMemorySize, 131072);

  // zero flags + h state + c state (ws is poisoned before every launch)
  hipMemsetAsync(ws, 0, ZERO_SPAN, stream);

  pack_xb_kernel  <<<13312, 256, 0, stream>>>(xt, xa, xv, xb);
  pack_whh_kernel <<<2048,  256, 0, stream>>>(W_hh, whh_p);
  pack_wih_kernel <<<832,   256, 0, stream>>>(W_ih, wih_p);
  pack_bias_kernel<<<16,    256, 0, stream>>>(b_ih, b_hh, bias);

  for (int c = 0; c < 8; ++c) {
    xg_gemm_kernel<<<dim3(64, 32), 256, 0, stream>>>(
        (const short8*)xb, (const short8*)wih_p, bias, xg, c);
    scan_kernel<<<256, 256, 131072, stream>>>(
        whh_p, xg, hb0, hb1, c_buf, h_final, flags, c);
  }
  mlp1_kernel<<<dim3(32, 8), 256, 0, stream>>>(h_final, W1, b1, hidden);
  mlp2_kernel<<<1, 256, 0, stream>>>(hidden, W2, b2, out);
}

// Round 8
// 2057.051 us; speedup vs baseline: 1.6461x; 1.6461x over previous
//
#include <hip/hip_runtime.h>
#include <cstdint>
#include <cstddef>

// ============================================================================
// EFLSTM: concat(x_text,x_audio,x_vision) -> LSTM(H=1024, T=256, B=256) -> MLP
//
// Round 8 = R5 skeleton + disjoint W streams + one fewer barrier.
//  - R7 lesson: wave-per-mtile made every wave read all 4 W quadrants
//    (512 KB/block/step, L1 can't dedup -> K-loop L2-bound) and its shfl-
//    packed scattered 8B stores amplified WRITE_SIZE 17.6->55 MB.
//  - R8 mapping: wave w <-> gate quadrant w. One 32 KB W stream per wave
//    (128 KB/block/step, ZERO duplication). A (all 4 mtiles) from shared
//    LDS staged via global_load_lds (SC0|SC1, IF-coherent).
//  - gates exchanged via LDS (R5-style gl), per-thread contiguous 8B h'
//    agent stores (no amplification), c in per-thread f32x4.
//  - Barriers/step: S1 (post-stage vmcnt drain — REQUIRED, R6 NaN lesson),
//    S3 (gates visible), S4 (pre-flag drain). S5 deleted: staging only
//    touches the A region whose reads are fenced by S4; gl(l+1) writes are
//    fenced by S1(l+1).
//  - No cache-wide fences anywhere (R5's 4.5x win).
// LDS: A 128 KB + gl 17 KB = 148480 B. 1 block/CU.
// ============================================================================

typedef __attribute__((ext_vector_type(8))) short short8;   // 8 x bf16
typedef __attribute__((ext_vector_type(4))) float f32x4;

#define MFMA_BF16(A,B,C) __builtin_amdgcn_mfma_f32_16x16x32_bf16((A),(B),(C),0,0,0)

// ---- workspace layout (bytes) ----
#define OFF_FLAGS 0u            // 256 * 4
#define OFF_HBUF0 4096u         // 256*1024*2 = 524288   (A-frag-linear bf16)
#define OFF_CBUF  528384u       // 256*1024*4 = 1048576  (fp32 cell state)
#define ZERO_SPAN 1576960u      // flags + hbuf0 + cbuf zeroed every launch
#define OFF_HBUF1 1576960u      // 524288
#define OFF_HFIN  2101248u      // 256*1024*4 = 1048576  (fp32 h_last)
#define OFF_HID   3149824u      // 256*512*4  = 524288   (fp32 mlp hidden)
#define OFF_BIAS  3674112u      // 4096*4
#define OFF_WHH   3690496u      // 64 slices * 64*1024 * 2 = 8388608
#define OFF_WIH   12079104u     // 256*13*64*8*2 = 3407872
#define OFF_XB    15486976u     // 4096*13*64*8*2 = 54525952
#define OFF_XG    70012928u     // 32*256*16*64*8 = 67108864 (bf16 C-frags)
#define WS_NEED   137121792ull

static __device__ __forceinline__ uint16_t f2bf(float f) {
  uint32_t u = __builtin_bit_cast(uint32_t, f);
  uint32_t r = u + 0x7FFFu + ((u >> 16) & 1u);   // round-nearest-even
  return (uint16_t)(r >> 16);
}
static __device__ __forceinline__ float bf2f_lo(uint32_t u) {
  return __builtin_bit_cast(float, u << 16);
}
static __device__ __forceinline__ float bf2f_hi(uint32_t u) {
  return __builtin_bit_cast(float, u & 0xFFFF0000u);
}
static __device__ __forceinline__ float sigm(float x) {
  return 1.0f / (1.0f + __expf(-x));
}
static __device__ __forceinline__ float tanh_f(float x) {
  float e = __expf(2.0f * x);
  return 1.0f - 2.0f / (e + 1.0f);
}
// async global->LDS, 16B/lane, aux=0x11 (SC0|SC1): IF-coherent read,
// bypasses the non-coherent per-XCD L2.
static __device__ __forceinline__ void gld_lds16_coh(const void* gsrc, void* ldst) {
  __builtin_amdgcn_global_load_lds(
      (const __attribute__((address_space(1))) uint32_t*)gsrc,
      (__attribute__((address_space(3))) uint32_t*)ldst, 16, 0, 0x11);
}

// ---------------------------------------------------------------------------
// pack x (3 tensors, fp32 [B,T,D_i]) -> xb bf16 A-frag-linear:
//   [mtile 4096][ks 13][lane 64][8], m = t*256+b, k padded to 416 with zeros
// ---------------------------------------------------------------------------
__global__ __launch_bounds__(256) void pack_xb_kernel(
    const float* __restrict__ xt, const float* __restrict__ xa,
    const float* __restrict__ xv, uint16_t* __restrict__ xb)
{
  int id = blockIdx.x * 256 + threadIdx.x;          // < 4096*13*64 = 3407872
  int lane = id & 63;
  int rem  = id >> 6;
  int ks = rem % 13;
  int mt = rem / 13;
  int m = mt * 16 + (lane & 15);
  int t = m >> 8;
  int b = m & 255;
  int k0 = ks * 32 + (lane >> 4) * 8;
  size_t base = (size_t)b * 256 + t;
  uint16_t vals[8];
#pragma unroll
  for (int e = 0; e < 8; ++e) {
    int k = k0 + e;
    float v;
    if (k < 300)      v = xt[base * 300 + k];
    else if (k < 374) v = xa[base * 74  + (k - 300)];
    else if (k < 409) v = xv[base * 35  + (k - 374)];
    else              v = 0.0f;
    vals[e] = f2bf(v);
  }
  uint32_t* d32 = (uint32_t*)(xb + (size_t)id * 8);
#pragma unroll
  for (int i = 0; i < 4; ++i)
    d32[i] = (uint32_t)vals[2*i] | ((uint32_t)vals[2*i+1] << 16);
}

// ---------------------------------------------------------------------------
// pack W_hh fp32 [4096,1024] -> bf16 B-frag-linear per scan block s:
//   [s 64][q 4][ks 32][lane 64][8], row = q*1024 + 16*s + (lane&15)
// ---------------------------------------------------------------------------
__global__ __launch_bounds__(256) void pack_whh_kernel(
    const float* __restrict__ whh, uint16_t* __restrict__ wp)
{
  int id = blockIdx.x * 256 + threadIdx.x;          // < 64*4*32*64 = 524288
  int lane = id & 63;
  int ks = (id >> 6) & 31;
  int q  = (id >> 11) & 3;
  int s  = id >> 13;
  int row = q * 1024 + s * 16 + (lane & 15);
  int k0 = ks * 32 + (lane >> 4) * 8;
  const float* src = whh + (size_t)row * 1024 + k0;
  uint16_t vals[8];
#pragma unroll
  for (int e = 0; e < 8; ++e) vals[e] = f2bf(src[e]);
  uint32_t* d32 = (uint32_t*)(wp + (size_t)id * 8);
#pragma unroll
  for (int i = 0; i < 4; ++i)
    d32[i] = (uint32_t)vals[2*i] | ((uint32_t)vals[2*i+1] << 16);
}

// ---------------------------------------------------------------------------
// pack W_ih fp32 [4096,409] -> bf16 B-frag-linear [nt 256][ks 13][lane][8]
// ---------------------------------------------------------------------------
__global__ __launch_bounds__(256) void pack_wih_kernel(
    const float* __restrict__ wih, uint16_t* __restrict__ wp)
{
  int id = blockIdx.x * 256 + threadIdx.x;          // < 256*13*64 = 212992
  int lane = id & 63;
  int rem = id >> 6;
  int ks = rem % 13;
  int nt = rem / 13;
  int n = nt * 16 + (lane & 15);
  int k0 = ks * 32 + (lane >> 4) * 8;
  uint16_t vals[8];
#pragma unroll
  for (int e = 0; e < 8; ++e) {
    int k = k0 + e;
    vals[e] = (k < 409) ? f2bf(wih[(size_t)n * 409 + k]) : (uint16_t)0;
  }
  uint32_t* d32 = (uint32_t*)(wp + (size_t)id * 8);
#pragma unroll
  for (int i = 0; i < 4; ++i)
    d32[i] = (uint32_t)vals[2*i] | ((uint32_t)vals[2*i+1] << 16);
}

__global__ __launch_bounds__(256) void pack_bias_kernel(
    const float* __restrict__ b_ih, const float* __restrict__ b_hh,
    float* __restrict__ bias)
{
  int id = blockIdx.x * 256 + threadIdx.x;          // < 4096
  bias[id] = b_ih[id] + b_hh[id];
}

// ---------------------------------------------------------------------------
// xg GEMM for one 32-step chunk: M=8192 (m=t*256+b), N=4096, K=416 (13 ksteps)
// grid (64, 32), 4 waves, wave tile 64x64. C written C-frag-linear bf16:
//   [t 32][nt 256][bt 16][lane 64][bf16x4]
// ---------------------------------------------------------------------------
__global__ __launch_bounds__(256) void xg_gemm_kernel(
    const short8* __restrict__ xb, const short8* __restrict__ wih,
    const float* __restrict__ bias, uint2* __restrict__ xg, int chunk)
{
  int tid = threadIdx.x;
  int lane = tid & 63;
  int w = tid >> 6;
  int wm = w & 1, wn = w >> 1;
  int bm = blockIdx.x, bn = blockIdx.y;
  int mtb = bm * 8 + wm * 4;          // local mtile base, 0..511
  int ntb = bn * 8 + wn * 4;          // ntile base, 0..255
  int col = lane & 15;

  f32x4 acc[4][4];
#pragma unroll
  for (int b = 0; b < 4; ++b) {
    float bv = bias[(ntb + b) * 16 + col];
    f32x4 v = {bv, bv, bv, bv};
#pragma unroll
    for (int a = 0; a < 4; ++a) acc[a][b] = v;
  }
  size_t mt_glob = (size_t)chunk * 512 + mtb;
  for (int ks = 0; ks < 13; ++ks) {
    short8 Af[4], Bf[4];
#pragma unroll
    for (int a = 0; a < 4; ++a)
      Af[a] = xb[((mt_glob + a) * 13 + ks) * 64 + lane];
#pragma unroll
    for (int b = 0; b < 4; ++b)
      Bf[b] = wih[(((size_t)(ntb + b)) * 13 + ks) * 64 + lane];
#pragma unroll
    for (int a = 0; a < 4; ++a)
#pragma unroll
      for (int b = 0; b < 4; ++b)
        acc[a][b] = MFMA_BF16(Af[a], Bf[b], acc[a][b]);
  }
#pragma unroll
  for (int a = 0; a < 4; ++a) {
    int mt = mtb + a;
    int t_loc = mt >> 4;
    int bt = mt & 15;
#pragma unroll
    for (int b = 0; b < 4; ++b) {
      size_t idx = (((size_t)t_loc * 256 + (ntb + b)) * 16 + bt) * 64 + lane;
      f32x4 v = acc[a][b];
      uint2 o;
      o.x = (uint32_t)f2bf(v[0]) | ((uint32_t)f2bf(v[1]) << 16);
      o.y = (uint32_t)f2bf(v[2]) | ((uint32_t)f2bf(v[3]) << 16);
      xg[idx] = o;
    }
  }
}

// ---------------------------------------------------------------------------
// Persistent scan: 256 blocks x 256 threads, 1 block/CU.
// group g = bid>>6 owns batch rows [64g,64g+64); slice s = bid&63 owns hidden
// units [16s,16s+16). Wave w <-> gate quadrant w (ONE 32 KB W stream/wave),
// loops over the 4 mtiles from the shared LDS A-tile. Per step:
//   issue 128 gld_lds (A, 128 KB, 32/wave) -> S1 (vmcnt drain, R6 lesson)
//   -> K loop: 4x ds_read_b128 A + 1 W L2 load + 4 MFMA per ks
//   -> gl write -> S3 -> in-thread elementwise (c f32x4) -> contiguous 8B
//   h' agent store -> S4 -> flag release -> xg prefetch -> all-lane poll.
// ---------------------------------------------------------------------------
__global__ __launch_bounds__(256, 1) void scan_kernel(
    const uint16_t* __restrict__ whh_p, const uint2* __restrict__ xg,
    uint16_t* __restrict__ hbuf0, uint16_t* __restrict__ hbuf1,
    float* __restrict__ c_buf, float* __restrict__ h_final,
    uint32_t* flags, int chunk)
{
  extern __shared__ char smem[];
  // smem[0      .. 131072): A tile, 4 mtiles x 32 ks x 64 lanes x 16 B
  // smem[131072 .. 148480): gate exchange, [64][68] fp32
  float* gl = (float*)(smem + 131072);

  const int tid = threadIdx.x;
  const int bid = blockIdx.x;
  const int g = bid >> 6, s = bid & 63;
  const int lane = tid & 63, w = tid >> 6;   // w = gate quadrant

  // wave-private W stream: quadrant w, frag at ks -> wstream[ks*64]
  const short8* wstream = (const short8*)(whh_p + (size_t)s * 65536)
                          + ((size_t)w * 32) * 64 + lane;

  // elementwise ownership: thread handles units col_e..col_e+3 of row R_e
  const int row_e = tid >> 2;                // 0..63
  const int j_e = (tid & 3) * 4;             // 0,4,8,12
  const int R_e = g * 64 + row_e;
  const int col_e = s * 16 + j_e;            // hidden col base
  f32x4 c4 = *(const f32x4*)(c_buf + (size_t)R_e * 1024 + col_e);

  // precompute h'-store address (4 consecutive bf16 = one aligned 8B store)
  size_t hstore_base;
  {
    int cg0 = col_e;
    int ksh = cg0 >> 5, quad = (cg0 >> 3) & 3, e0 = cg0 & 7;
    int mth = row_e >> 4;
    int laneh = quad * 16 + (row_e & 15);
    hstore_base = (((size_t)(g * 4 + mth) * 32 + ksh) * 64 + laneh) * 8 + e0;
  }

  const short8* Afrag = (const short8*)smem;
  const int myflag = g * 64 + lane;

  // xg prefetch for step 0: wave w needs quadrant w x all 4 mtiles
  uint2 xp[4];
#pragma unroll
  for (int a = 0; a < 4; ++a)
    xp[a] = xg[(((size_t)0 * 256 + (w * 64 + s)) * 16 + (g * 4 + a)) * 64 + lane];

  for (int l = 0; l < 32; ++l) {
    const int ts = chunk * 32 + l;
    const uint16_t* hin = (ts & 1) ? hbuf1 : hbuf0;
    uint16_t* hout = (ts & 1) ? hbuf0 : hbuf1;

    // ---- stage this step's A h-tile into LDS: 128 x (1 KB), 32 per wave ----
    {
      const uint16_t* gbase = hin + (size_t)g * 65536
                              + (size_t)(w * 32) * 512 + (size_t)lane * 8;
      char* lbase = smem + (size_t)(w * 32) * 1024;
#pragma unroll
      for (int p = 0; p < 32; ++p)
        gld_lds16_coh(gbase + (size_t)p * 512, lbase + p * 1024);
    }

    // acc init from prefetched bf16 xg (bias folded in at gemm time)
    f32x4 acc[4];
#pragma unroll
    for (int a = 0; a < 4; ++a) {
      uint2 p = xp[a];
      f32x4 v = {bf2f_lo(p.x), bf2f_hi(p.x), bf2f_lo(p.y), bf2f_hi(p.y)};
      acc[a] = v;
    }

    __syncthreads();   // S1: vmcnt(0) drain — async LDS writes are NOT
                       // auto-ordered before ds_read (R6 NaN lesson)

    // ---- K loop: one W L2 stream, 4 A ds_reads, 4 MFMA per ks ----
#pragma unroll
    for (int ks = 0; ks < 32; ++ks) {
      short8 W = wstream[ks * 64];
      short8 A0 = Afrag[(0 * 32 + ks) * 64 + lane];
      short8 A1 = Afrag[(1 * 32 + ks) * 64 + lane];
      short8 A2 = Afrag[(2 * 32 + ks) * 64 + lane];
      short8 A3 = Afrag[(3 * 32 + ks) * 64 + lane];
      acc[0] = MFMA_BF16(A0, W, acc[0]);
      acc[1] = MFMA_BF16(A1, W, acc[1]);
      acc[2] = MFMA_BF16(A2, W, acc[2]);
      acc[3] = MFMA_BF16(A3, W, acc[3]);
    }

    // gates -> LDS  (C layout: col=lane&15, row=(lane>>4)*4+reg)
    {
      int r0 = (lane >> 4) * 4;
      int cc = lane & 15;
      int colc = w * 16 + cc;
#pragma unroll
      for (int a = 0; a < 4; ++a)
#pragma unroll
        for (int r = 0; r < 4; ++r)
          gl[(a * 16 + r0 + r) * 68 + colc] = acc[a][r];
    }
    __syncthreads();   // S3: gates visible (A-tile reads also complete)

    // LSTM elementwise (PyTorch gate order i,f,g,o)
    float hv[4];
#pragma unroll
    for (int u = 0; u < 4; ++u) {
      int cj = j_e + u;
      float xi = gl[row_e * 68 + cj];
      float xf = gl[row_e * 68 + 16 + cj];
      float xg_ = gl[row_e * 68 + 32 + cj];
      float xo = gl[row_e * 68 + 48 + cj];
      float cn = sigm(xf) * c4[u] + sigm(xi) * tanh_f(xg_);
      c4[u] = cn;
      hv[u] = sigm(xo) * tanh_f(cn);
    }
    // h' as ONE contiguous 8-byte agent-scope store per thread
    {
      uint32_t w0 = (uint32_t)f2bf(hv[0]) | ((uint32_t)f2bf(hv[1]) << 16);
      uint32_t w1 = (uint32_t)f2bf(hv[2]) | ((uint32_t)f2bf(hv[3]) << 16);
      unsigned long long v = ((unsigned long long)w1 << 32) | w0;
      __hip_atomic_store((unsigned long long*)(hout + hstore_base), v,
                         __ATOMIC_RELAXED, __HIP_MEMORY_SCOPE_AGENT);
    }
    if (chunk == 7 && l == 31) {
      f32x4 hh = {hv[0], hv[1], hv[2], hv[3]};
      *(f32x4*)(h_final + (size_t)R_e * 1024 + col_e) = hh;
    }
    if (l != 31) {
      // ---- group-local barrier (64 blocks of group g), fence-free ----
      __syncthreads();   // S4: drains every wave's h' stores
      if (tid == 0) {
        __hip_atomic_store(&flags[bid], (uint32_t)(ts + 1),
                           __ATOMIC_RELAXED, __HIP_MEMORY_SCOPE_AGENT);
      }
      // prefetch next step's xg while waiting (xg constant during scan)
      {
        int ln = l + 1;
#pragma unroll
        for (int a = 0; a < 4; ++a)
          xp[a] = xg[(((size_t)ln * 256 + (w * 64 + s)) * 16 + (g * 4 + a)) * 64 + lane];
      }
      // all lanes poll one peer flag each; wave proceeds when all 64 peers
      // released. No S5: staging only overwrites the A region (reads fenced
      // by S4); gl(l+1) writes are fenced by S1(l+1).
      while (__hip_atomic_load(&flags[myflag], __ATOMIC_RELAXED,
                               __HIP_MEMORY_SCOPE_AGENT) < (uint32_t)(ts + 1)) {
        __builtin_amdgcn_s_sleep(1);
      }
    }
  }
  *(f32x4*)(c_buf + (size_t)R_e * 1024 + col_e) = c4;
}

// ---------------------------------------------------------------------------
// MLP layer 1: hidden = relu(h_last @ W1^T + b1), fp32 VALU.
// ---------------------------------------------------------------------------
__global__ __launch_bounds__(256) void mlp1_kernel(
    const float* __restrict__ h_final, const float* __restrict__ W1,
    const float* __restrict__ b1, float* __restrict__ hidden)
{
  __shared__ float hl[8 * 1024];       // 32 KB
  __shared__ float part[4 * 64 * 8];   // 8 KB
  int tid = threadIdx.x;
  int rb = blockIdx.x;                 // 0..31
  int cb = blockIdx.y;                 // 0..7
  const f32x4* hsrc = (const f32x4*)(h_final + (size_t)rb * 8 * 1024);
  for (int i = tid; i < 2048; i += 256) ((f32x4*)hl)[i] = hsrc[i];
  __syncthreads();
  int cell_l = tid & 63;
  int kq = tid >> 6;                   // k quarter
  int cell = cb * 64 + cell_l;
  float accv[8] = {0,0,0,0,0,0,0,0};
  const f32x4* wrow = (const f32x4*)(W1 + (size_t)cell * 1024) + kq * 64;
  const f32x4* hl4 = (const f32x4*)hl;
  for (int k4 = 0; k4 < 64; ++k4) {
    f32x4 wv = wrow[k4];
    int kidx = kq * 64 + k4;
#pragma unroll
    for (int r = 0; r < 8; ++r) {
      f32x4 hv = hl4[r * 256 + kidx];
      accv[r] += wv[0] * hv[0] + wv[1] * hv[1] + wv[2] * hv[2] + wv[3] * hv[3];
    }
  }
#pragma unroll
  for (int r = 0; r < 8; ++r) part[(kq * 64 + cell_l) * 8 + r] = accv[r];
  __syncthreads();
#pragma unroll
  for (int rr = 0; rr < 2; ++rr) {
    int r = kq * 2 + rr;
    float sum = b1[cell];
    for (int q = 0; q < 4; ++q) sum += part[(q * 64 + cell_l) * 8 + r];
    hidden[(size_t)(rb * 8 + r) * 512 + cell] = fmaxf(sum, 0.0f);
  }
}

// MLP layer 2: out[b] = hidden[b] . W2 + b2
__global__ __launch_bounds__(256) void mlp2_kernel(
    const float* __restrict__ hidden, const float* __restrict__ W2,
    const float* __restrict__ b2, float* __restrict__ out)
{
  __shared__ float w2l[512];
  int tid = threadIdx.x;
  for (int i = tid; i < 512; i += 256) w2l[i] = W2[i];
  __syncthreads();
  const f32x4* hrow = (const f32x4*)(hidden + (size_t)tid * 512);
  const f32x4* w4 = (const f32x4*)w2l;
  float acc = b2[0];
  for (int k = 0; k < 128; ++k) {
    f32x4 a = hrow[k], b = w4[k];
    acc += a[0] * b[0] + a[1] * b[1] + a[2] * b[2] + a[3] * b[3];
  }
  out[tid] = acc;
}

// ---------------------------------------------------------------------------
extern "C" void kernel_launch(void* const* d_in, const int* in_sizes, int n_in,
                              void* d_out, int out_size, void* d_ws, size_t ws_size,
                              hipStream_t stream)
{
  (void)in_sizes; (void)n_in; (void)out_size;
  if (ws_size < WS_NEED) return;   // workspace too small -> loud bench failure

  const float* xt   = (const float*)d_in[0];
  const float* xa   = (const float*)d_in[1];
  const float* xv   = (const float*)d_in[2];
  const float* W_ih = (const float*)d_in[3];
  const float* W_hh = (const float*)d_in[4];
  const float* b_ih = (const float*)d_in[5];
  const float* b_hh = (const float*)d_in[6];
  const float* W1   = (const float*)d_in[7];
  const float* b1   = (const float*)d_in[8];
  const float* W2   = (const float*)d_in[9];
  const float* b2   = (const float*)d_in[10];
  float* out = (float*)d_out;
  char* ws = (char*)d_ws;

  uint32_t* flags   = (uint32_t*)(ws + OFF_FLAGS);
  uint16_t* hb0     = (uint16_t*)(ws + OFF_HBUF0);
  uint16_t* hb1     = (uint16_t*)(ws + OFF_HBUF1);
  float*    c_buf   = (float*)(ws + OFF_CBUF);
  float*    h_final = (float*)(ws + OFF_HFIN);
  float*    hidden  = (float*)(ws + OFF_HID);
  float*    bias    = (float*)(ws + OFF_BIAS);
  uint16_t* whh_p   = (uint16_t*)(ws + OFF_WHH);
  uint16_t* wih_p   = (uint16_t*)(ws + OFF_WIH);
  uint16_t* xb      = (uint16_t*)(ws + OFF_XB);
  uint2*    xg      = (uint2*)(ws + OFF_XG);

  // allow >64KB dynamic LDS for the scan kernel (idempotent, capture-safe)
  hipFuncSetAttribute((const void*)scan_kernel,
                      hipFuncAttributeMaxDynamicSharedMemorySize, 148480);

  // zero flags + h state + c state (ws is poisoned before every launch)
  hipMemsetAsync(ws, 0, ZERO_SPAN, stream);

  pack_xb_kernel  <<<13312, 256, 0, stream>>>(xt, xa, xv, xb);
  pack_whh_kernel <<<2048,  256, 0, stream>>>(W_hh, whh_p);
  pack_wih_kernel <<<832,   256, 0, stream>>>(W_ih, wih_p);
  pack_bias_kernel<<<16,    256, 0, stream>>>(b_ih, b_hh, bias);

  for (int c = 0; c < 8; ++c) {
    xg_gemm_kernel<<<dim3(64, 32), 256, 0, stream>>>(
        (const short8*)xb, (const short8*)wih_p, bias, xg, c);
    scan_kernel<<<256, 256, 148480, stream>>>(
        whh_p, xg, hb0, hb1, c_buf, h_final, flags, c);
  }
  mlp1_kernel<<<dim3(32, 8), 256, 0, stream>>>(h_final, W1, b1, hidden);
  mlp2_kernel<<<1, 256, 0, stream>>>(hidden, W2, b2, out);
}